// Round 4
// baseline (176.380 us; speedup 1.0000x reference)
//
#include <hip/hip_runtime.h>
#include <math.h>

#define NUM_EMB 512
#define DIMV 65          // 65
#define DD   64          // DIM-1
#define BB   2048
#define NN   256
#define XPITCH 132       // xT row pitch (128 rows + 4 pad), %4==0 for b128

__device__ __forceinline__ float gelu_exact(float x) {
    return 0.5f * x * (1.0f + erff(x * 0.7071067811865475f));
}

// ---------------------------------------------------------------------------
// Kernel 1: build W[e] = H0 @ ... @ H63, scale last column, store NATURAL
// row-major W[e][d][c]. Householder right-multiply as matvec + rank-1
// update: W <- W - (2/||v||^2) (W v) v^T. Echoes r_idx into out tail.
// ---------------------------------------------------------------------------
__global__ __launch_bounds__(256) void build_W(const float* __restrict__ emb,
                                               const float* __restrict__ flip_sign,
                                               const int*   __restrict__ r_idx,
                                               float* __restrict__ Wg,
                                               float* __restrict__ out) {
    __shared__ float v_lds[DD * DD];
    __shared__ float s_lds[DD];
    const int e = blockIdx.x;
    const int t = threadIdx.x;
    const int r = t >> 2;
    const int q = t & 3;

    const float* erow = emb + (size_t)e * (DD * DD);
    #pragma unroll
    for (int p = 0; p < 16; ++p) {
        int idx = p * 256 + t;
        v_lds[idx] = gelu_exact(erow[idx]);
    }

    if (t < 4) {
        int bi = e * 4 + t;
        out[(size_t)BB * NN * DIMV + bi] = (float)r_idx[bi];
    }
    __syncthreads();

    {
        const float* vr = &v_lds[r * DD + q * 16];
        float ss = 0.f;
        #pragma unroll
        for (int k = 0; k < 16; ++k) ss += vr[k] * vr[k];
        ss += __shfl_xor(ss, 1);
        ss += __shfl_xor(ss, 2);
        if (q == 0) s_lds[r] = 2.0f / ss;
    }
    __syncthreads();

    float Wq[16];
    #pragma unroll
    for (int k = 0; k < 16; ++k) Wq[k] = ((q * 16 + k) == r) ? 1.0f : 0.0f;

    for (int w = 0; w < DD; ++w) {
        const float* vr = &v_lds[w * DD + q * 16];
        float vv[16];
        *(float4*)&vv[0]  = *(const float4*)&vr[0];
        *(float4*)&vv[4]  = *(const float4*)&vr[4];
        *(float4*)&vv[8]  = *(const float4*)&vr[8];
        *(float4*)&vv[12] = *(const float4*)&vr[12];
        float p0 = Wq[0] * vv[0],  p1 = Wq[1] * vv[1];
        float p2 = Wq[2] * vv[2],  p3 = Wq[3] * vv[3];
        #pragma unroll
        for (int k = 4; k < 16; k += 4) {
            p0 += Wq[k]     * vv[k];
            p1 += Wq[k + 1] * vv[k + 1];
            p2 += Wq[k + 2] * vv[k + 2];
            p3 += Wq[k + 3] * vv[k + 3];
        }
        float p = (p0 + p1) + (p2 + p3);
        p += __shfl_xor(p, 1);
        p += __shfl_xor(p, 2);
        const float sc = s_lds[w] * p;
        #pragma unroll
        for (int k = 0; k < 16; ++k) Wq[k] -= sc * vv[k];
    }

    if (q == 3) Wq[15] *= flip_sign[0];

    float* wd = Wg + (((size_t)e * DD + r) * DD) + q * 16;
    *(float4*)&wd[0]  = *(float4*)&Wq[0];
    *(float4*)&wd[4]  = *(float4*)&Wq[4];
    *(float4*)&wd[8]  = *(float4*)&Wq[8];
    *(float4*)&wd[12] = *(float4*)&Wq[12];
}

// ---------------------------------------------------------------------------
// Kernel 2: block = 256 threads, 128-row tile of one b, all 64 cols.
//  - W[64][64] natural in LDS (16 KB): read Wl[d][8j..] as 2 b128, 2-way=free.
//  - x tile TRANSPOSED d-major in LDS: xT[d][row], pitch 132 (16B-aligned
//    rows, read banks (4d+4i)%32 conflict-free). Staged via flat coalesced
//    float4 loads + per-element transposed b32 writes; col-0 passthrough
//    fused into staging.
//  - Thread (i=t>>3, j=t&7): 4 rows x 8 cols microtile -> 3 LDS instr per
//    32 FMAs; unroll 16 => all LDS reads use immediate offsets.
//  - LDS 50176 B -> 3 blocks/CU (12 waves).
// ---------------------------------------------------------------------------
__global__ __launch_bounds__(256, 3) void apply_W(const float* __restrict__ x,
                                                  const int*   __restrict__ r_idx,
                                                  const float* __restrict__ Wg,
                                                  float* __restrict__ out) {
    __shared__ alignas(16) float Wl[DD * DD];        // 16384 B
    __shared__ alignas(16) float xT[DD * XPITCH];    // 33792 B
    const int blk  = blockIdx.x;
    const int b    = blk >> 1;
    const int half = blk & 1;
    const size_t rowbase = (size_t)b * NN + half * 128;
    const int t = threadIdx.x;

    const int e = r_idx[b];

    // stage W: 1024 float4, coalesced
    {
        const float4* ws = (const float4*)(Wg + (size_t)e * (DD * DD));
        float4* wd = (float4*)Wl;
        #pragma unroll
        for (int p = 0; p < 4; ++p) wd[p * 256 + t] = ws[p * 256 + t];
    }

    // stage x: flat coalesced float4 over 128*65 = 8320 floats (2080 float4),
    // scatter to xT[(col-1)*XPITCH + row]; col==0 goes straight to out.
    {
        const float4* xs = (const float4*)(x + rowbase * DIMV);
        #pragma unroll
        for (int it = 0; it < 9; ++it) {
            int idx = it * 256 + t;
            if (idx < 2080) {
                float4 v = xs[idx];
                int flat = idx * 4;
                #pragma unroll
                for (int k = 0; k < 4; ++k) {
                    int f = flat + k;
                    int row = f / DIMV;          // mul-hi magic, no real div
                    int col = f - row * DIMV;
                    float val = (k == 0) ? v.x : (k == 1) ? v.y : (k == 2) ? v.z : v.w;
                    if (col == 0) out[(rowbase + row) * DIMV] = val;
                    else          xT[(col - 1) * XPITCH + row] = val;
                }
            }
        }
    }
    __syncthreads();

    const int i = t >> 3;    // 0..31 : rows 4i..4i+3
    const int j = t & 7;     // 0..7  : cols 8j..8j+7

    float acc[4][8];
    #pragma unroll
    for (int k = 0; k < 4; ++k)
        #pragma unroll
        for (int m = 0; m < 8; ++m) acc[k][m] = 0.f;

    const float* xp = &xT[4 * i];
    const float* wp = &Wl[8 * j];

    #pragma unroll 16
    for (int d = 0; d < DD; ++d) {
        const float4 xv = *(const float4*)&xp[d * XPITCH];
        const float4 w0 = *(const float4*)&wp[d * DD];
        const float4 w1 = *(const float4*)&wp[d * DD + 4];
        const float xs4[4] = {xv.x, xv.y, xv.z, xv.w};
        const float wc[8]  = {w0.x, w0.y, w0.z, w0.w, w1.x, w1.y, w1.z, w1.w};
        #pragma unroll
        for (int k = 0; k < 4; ++k)
            #pragma unroll
            for (int m = 0; m < 8; ++m)
                acc[k][m] += xs4[k] * wc[m];
    }

    // store 4 rows x 8 cols per thread
    #pragma unroll
    for (int k = 0; k < 4; ++k) {
        float* op = out + (rowbase + 4 * i + k) * DIMV + 1 + 8 * j;
        #pragma unroll
        for (int m = 0; m < 8; ++m) op[m] = acc[k][m];
    }
}

extern "C" void kernel_launch(void* const* d_in, const int* in_sizes, int n_in,
                              void* d_out, int out_size, void* d_ws, size_t ws_size,
                              hipStream_t stream) {
    const float* x         = (const float*)d_in[0];
    const int*   r_idx     = (const int*)d_in[1];
    const float* emb       = (const float*)d_in[2];
    const float* flip_sign = (const float*)d_in[3];
    float* out = (float*)d_out;
    float* Wg  = (float*)d_ws;   // 512 * 64 * 64 * 4 = 8 MB scratch

    build_W<<<NUM_EMB, 256, 0, stream>>>(emb, flip_sign, r_idx, Wg, out);
    apply_W<<<BB * 2, 256, 0, stream>>>(x, r_idx, Wg, out);
}

// Round 5
// 106.262 us; speedup vs baseline: 1.6599x; 1.6599x over previous
//
#include <hip/hip_runtime.h>
#include <math.h>

#define NUM_EMB 512
#define DIMV 65          // 65
#define DD   64          // DIM-1
#define BB   2048
#define NN   256
#define XP   68          // stripped-x LDS pitch: %4==0 (16B rows), 68%8==4 ->
                         // strided-row b128 reads tile all 32 banks

__device__ __forceinline__ float gelu_exact(float x) {
    return 0.5f * x * (1.0f + erff(x * 0.7071067811865475f));
}

// ---------------------------------------------------------------------------
// Kernel 1: build W[e] = H0 @ ... @ H63, scale last column, store natural
// row-major W[e][d][c]. Householder right-multiply as matvec + rank-1
// update: W <- W - (2/||v||^2) (W v) v^T. Echoes r_idx into out tail.
// ---------------------------------------------------------------------------
__global__ __launch_bounds__(256) void build_W(const float* __restrict__ emb,
                                               const float* __restrict__ flip_sign,
                                               const int*   __restrict__ r_idx,
                                               float* __restrict__ Wg,
                                               float* __restrict__ out) {
    __shared__ float v_lds[DD * DD];
    __shared__ float s_lds[DD];
    const int e = blockIdx.x;
    const int t = threadIdx.x;
    const int r = t >> 2;
    const int q = t & 3;

    const float* erow = emb + (size_t)e * (DD * DD);
    #pragma unroll
    for (int p = 0; p < 16; ++p) {
        int idx = p * 256 + t;
        v_lds[idx] = gelu_exact(erow[idx]);
    }

    if (t < 4) {
        int bi = e * 4 + t;
        out[(size_t)BB * NN * DIMV + bi] = (float)r_idx[bi];
    }
    __syncthreads();

    {
        const float* vr = &v_lds[r * DD + q * 16];
        float ss = 0.f;
        #pragma unroll
        for (int k = 0; k < 16; ++k) ss += vr[k] * vr[k];
        ss += __shfl_xor(ss, 1);
        ss += __shfl_xor(ss, 2);
        if (q == 0) s_lds[r] = 2.0f / ss;
    }
    __syncthreads();

    float Wq[16];
    #pragma unroll
    for (int k = 0; k < 16; ++k) Wq[k] = ((q * 16 + k) == r) ? 1.0f : 0.0f;

    for (int w = 0; w < DD; ++w) {
        const float* vr = &v_lds[w * DD + q * 16];
        float vv[16];
        *(float4*)&vv[0]  = *(const float4*)&vr[0];
        *(float4*)&vv[4]  = *(const float4*)&vr[4];
        *(float4*)&vv[8]  = *(const float4*)&vr[8];
        *(float4*)&vv[12] = *(const float4*)&vr[12];
        float p0 = Wq[0] * vv[0],  p1 = Wq[1] * vv[1];
        float p2 = Wq[2] * vv[2],  p3 = Wq[3] * vv[3];
        #pragma unroll
        for (int k = 4; k < 16; k += 4) {
            p0 += Wq[k]     * vv[k];
            p1 += Wq[k + 1] * vv[k + 1];
            p2 += Wq[k + 2] * vv[k + 2];
            p3 += Wq[k + 3] * vv[k + 3];
        }
        float p = (p0 + p1) + (p2 + p3);
        p += __shfl_xor(p, 1);
        p += __shfl_xor(p, 2);
        const float sc = s_lds[w] * p;
        #pragma unroll
        for (int k = 0; k < 16; ++k) Wq[k] -= sc * vv[k];
    }

    if (q == 3) Wq[15] *= flip_sign[0];

    float* wd = Wg + (((size_t)e * DD + r) * DD) + q * 16;
    *(float4*)&wd[0]  = *(float4*)&Wq[0];
    *(float4*)&wd[4]  = *(float4*)&Wq[4];
    *(float4*)&wd[8]  = *(float4*)&Wq[8];
    *(float4*)&wd[12] = *(float4*)&Wq[12];
}

// ---------------------------------------------------------------------------
// Kernel 2: block = 256 threads (4 waves), 128-row tile of one b.
//  - W[64][64] natural in LDS; read W[d][8j..8j+7] as 2 b128 (2-way = free).
//  - x stripped of col0 into Xs[row*68 + d] (R2-proven conflict-free staging:
//    64 consecutive global dwords per row, consecutive LDS dwords).
//  - Thread (i=t>>3, j=t&7) computes rows {i, i+32, i+64, i+96} x cols
//    {8j..8j+7}: per 4-d chunk 4+8 ds_read_b128 feed 128 wave-FMAs.
//    Strided rows make the 8 per-wave x-read spans tile all 32 banks.
//  - Col-0 passthrough from X0[] LDS, written WITH the compute stores so
//    every out line is filled by one wave at one time (no double-write).
//  - LDS 50.5 KB -> 3 blocks/CU (12 waves).
// ---------------------------------------------------------------------------
__global__ __launch_bounds__(256, 3) void apply_W(const float* __restrict__ x,
                                                  const int*   __restrict__ r_idx,
                                                  const float* __restrict__ Wg,
                                                  float* __restrict__ out) {
    __shared__ alignas(16) float Wl[DD * DD];     // 16384 B
    __shared__ alignas(16) float Xs[128 * XP];    // 34816 B
    __shared__ float X0[128];                     // 512 B
    const int blk  = blockIdx.x;
    const int b    = blk >> 1;
    const int half = blk & 1;
    const size_t rowbase = (size_t)b * NN + half * 128;
    const int t = threadIdx.x;

    const int e = r_idx[b];

    // stage W: 1024 float4, coalesced
    {
        const float4* ws = (const float4*)(Wg + (size_t)e * (DD * DD));
        float4* wd = (float4*)Wl;
        #pragma unroll
        for (int p = 0; p < 4; ++p) wd[p * 256 + t] = ws[p * 256 + t];
    }

    // stage x stripped: Xs[row*XP + d] = x[rowbase+row][1+d]
    {
        const float* xb = x + rowbase * DIMV;
        const int lane = t & 63;
        const int wv   = t >> 6;
        #pragma unroll
        for (int k = 0; k < 16; ++k) {
            int row = wv + 4 * k;
            Xs[row * XP + lane] = xb[row * DIMV + 1 + lane];
        }
        if (t < 128) X0[t] = xb[t * DIMV];   // lines are L1/L2-hot from stage
    }
    __syncthreads();

    const int i = t >> 3;   // 0..31
    const int j = t & 7;    // 0..7

    float acc[4][8];
    #pragma unroll
    for (int s = 0; s < 4; ++s)
        #pragma unroll
        for (int m = 0; m < 8; ++m) acc[s][m] = 0.f;

    const float* xp0 = &Xs[i * XP];
    const float* wp  = &Wl[8 * j];

    #pragma unroll 4
    for (int dc = 0; dc < 16; ++dc) {
        float4 xv0 = *(const float4*)&xp0[0 * 32 * XP + 4 * dc];
        float4 xv1 = *(const float4*)&xp0[1 * 32 * XP + 4 * dc];
        float4 xv2 = *(const float4*)&xp0[2 * 32 * XP + 4 * dc];
        float4 xv3 = *(const float4*)&xp0[3 * 32 * XP + 4 * dc];
        #pragma unroll
        for (int dd = 0; dd < 4; ++dd) {
            const int d = 4 * dc + dd;
            const float4 w0 = *(const float4*)&wp[d * DD];
            const float4 w1 = *(const float4*)&wp[d * DD + 4];
            const float wc[8] = {w0.x, w0.y, w0.z, w0.w, w1.x, w1.y, w1.z, w1.w};
            const float x0 = (dd == 0) ? xv0.x : (dd == 1) ? xv0.y : (dd == 2) ? xv0.z : xv0.w;
            const float x1 = (dd == 0) ? xv1.x : (dd == 1) ? xv1.y : (dd == 2) ? xv1.z : xv1.w;
            const float x2 = (dd == 0) ? xv2.x : (dd == 1) ? xv2.y : (dd == 2) ? xv2.z : xv2.w;
            const float x3 = (dd == 0) ? xv3.x : (dd == 1) ? xv3.y : (dd == 2) ? xv3.z : xv3.w;
            #pragma unroll
            for (int m = 0; m < 8; ++m) {
                acc[0][m] += x0 * wc[m];
                acc[1][m] += x1 * wc[m];
                acc[2][m] += x2 * wc[m];
                acc[3][m] += x3 * wc[m];
            }
        }
    }

    // store: 4 strided rows x 8 cols; j==0 also writes the col-0 passthrough
    #pragma unroll
    for (int s = 0; s < 4; ++s) {
        const int row = i + 32 * s;
        float* op = out + (rowbase + row) * DIMV + 1 + 8 * j;
        if (j == 0) op[-1] = X0[row];
        #pragma unroll
        for (int m = 0; m < 8; ++m) op[m] = acc[s][m];
    }
}

extern "C" void kernel_launch(void* const* d_in, const int* in_sizes, int n_in,
                              void* d_out, int out_size, void* d_ws, size_t ws_size,
                              hipStream_t stream) {
    const float* x         = (const float*)d_in[0];
    const int*   r_idx     = (const int*)d_in[1];
    const float* emb       = (const float*)d_in[2];
    const float* flip_sign = (const float*)d_in[3];
    float* out = (float*)d_out;
    float* Wg  = (float*)d_ws;   // 512 * 64 * 64 * 4 = 8 MB scratch

    build_W<<<NUM_EMB, 256, 0, stream>>>(emb, flip_sign, r_idx, Wg, out);
    apply_W<<<BB * 2, 256, 0, stream>>>(x, r_idx, Wg, out);
}

// Round 6
// 89.064 us; speedup vs baseline: 1.9804x; 1.1931x over previous
//
#include <hip/hip_runtime.h>
#include <math.h>

#define NUM_EMB 512
#define DIMV 65          // 65
#define DD   64          // DIM-1
#define BB   2048
#define NN   256

typedef short short8 __attribute__((ext_vector_type(8)));   // 8 bf16 (4 VGPR)
typedef float f32x4  __attribute__((ext_vector_type(4)));   // MFMA acc

__device__ __forceinline__ float gelu_exact(float x) {
    return 0.5f * x * (1.0f + erff(x * 0.7071067811865475f));
}

// fp32 -> bf16, round-to-nearest-even, deterministic
__device__ __forceinline__ unsigned short f2bf(float f) {
    unsigned u = __builtin_bit_cast(unsigned, f);
    u += 0x7FFFu + ((u >> 16) & 1u);
    return (unsigned short)(u >> 16);
}

// ---------------------------------------------------------------------------
// Kernel 1: build W[e] = H0 @ ... @ H63 (Householder matvec + rank-1 update),
// scale last column, store TRANSPOSED bf16: WgT[e][c][d] = bf16(W[e][d][c]).
// Software-pipelined vv prefetch hides the per-step LDS latency.
// Echoes r_idx into the out tail.
// ---------------------------------------------------------------------------
__global__ __launch_bounds__(256) void build_W(const float* __restrict__ emb,
                                               const float* __restrict__ flip_sign,
                                               const int*   __restrict__ r_idx,
                                               unsigned short* __restrict__ WgT,
                                               float* __restrict__ out) {
    __shared__ float v_lds[DD * DD];
    __shared__ float s_lds[DD];
    const int e = blockIdx.x;
    const int t = threadIdx.x;
    const int r = t >> 2;
    const int q = t & 3;

    const float* erow = emb + (size_t)e * (DD * DD);
    #pragma unroll
    for (int p = 0; p < 16; ++p) {
        int idx = p * 256 + t;
        v_lds[idx] = gelu_exact(erow[idx]);
    }

    // r_idx passthrough: output 1 lives at out[BB*NN*DIMV + b]
    if (t < 4) {
        int bi = e * 4 + t;
        out[(size_t)BB * NN * DIMV + bi] = (float)r_idx[bi];
    }
    __syncthreads();

    {
        const float* vr = &v_lds[r * DD + q * 16];
        float ss = 0.f;
        #pragma unroll
        for (int k = 0; k < 16; ++k) ss += vr[k] * vr[k];
        ss += __shfl_xor(ss, 1);
        ss += __shfl_xor(ss, 2);
        if (q == 0) s_lds[r] = 2.0f / ss;
    }
    __syncthreads();

    float Wq[16];
    #pragma unroll
    for (int k = 0; k < 16; ++k) Wq[k] = ((q * 16 + k) == r) ? 1.0f : 0.0f;

    // prefetch vv for w=0
    float vv[16], nv[16];
    {
        const float* vr = &v_lds[q * 16];
        *(float4*)&nv[0]  = *(const float4*)&vr[0];
        *(float4*)&nv[4]  = *(const float4*)&vr[4];
        *(float4*)&nv[8]  = *(const float4*)&vr[8];
        *(float4*)&nv[12] = *(const float4*)&vr[12];
    }

    for (int w = 0; w < DD; ++w) {
        #pragma unroll
        for (int k = 0; k < 16; ++k) vv[k] = nv[k];
        if (w < DD - 1) {   // prefetch next step's vector (independent of Wq)
            const float* vr = &v_lds[(w + 1) * DD + q * 16];
            *(float4*)&nv[0]  = *(const float4*)&vr[0];
            *(float4*)&nv[4]  = *(const float4*)&vr[4];
            *(float4*)&nv[8]  = *(const float4*)&vr[8];
            *(float4*)&nv[12] = *(const float4*)&vr[12];
        }
        float p0 = Wq[0] * vv[0],  p1 = Wq[1] * vv[1];
        float p2 = Wq[2] * vv[2],  p3 = Wq[3] * vv[3];
        #pragma unroll
        for (int k = 4; k < 16; k += 4) {
            p0 += Wq[k]     * vv[k];
            p1 += Wq[k + 1] * vv[k + 1];
            p2 += Wq[k + 2] * vv[k + 2];
            p3 += Wq[k + 3] * vv[k + 3];
        }
        float p = (p0 + p1) + (p2 + p3);
        p += __shfl_xor(p, 1);
        p += __shfl_xor(p, 2);
        const float sc = s_lds[w] * p;
        #pragma unroll
        for (int k = 0; k < 16; ++k) Wq[k] -= sc * vv[k];
    }

    // W[:, :, -1] *= flip_sign  (column 63 = q==3, k==15)
    if (q == 3) Wq[15] *= flip_sign[0];

    // store transposed bf16: WgT[e][c][d] with c = 16q+k, d = r
    unsigned short* wd = WgT + (size_t)e * (DD * DD) + r;
    #pragma unroll
    for (int k = 0; k < 16; ++k)
        wd[(16 * q + k) * DD] = f2bf(Wq[k]);
}

// ---------------------------------------------------------------------------
// Kernel 2 (MFMA): out[.,0]=x[.,0]; out[.,1+c] = sum_d x[.,1+d]*W[d][c].
// Block = 256 threads (4 waves), 128-row tile of one b. bf16 operands.
//  - A in LDS: As[row][64 k] bf16, XOR-swizzled (byte ^= (row&7)<<4) so the
//    16-lane/row fragment ds_read_b128 is conflict-free (2-way = free).
//  - B in LDS: Bs[col][64 k] bf16 (from prebuilt bf16 W^T), same swizzle.
//  - Wave w: rows [32w,32w+32) x all 64 cols = 2x4 tiles of 16x16, K=64 ->
//    12 ds_read_b128 + 16 mfma_f32_16x16x32_bf16 per wave.
//  - C/D layout (HW-verified): col = lane&15, row = (lane>>4)*4 + reg.
//  - LDS 24.6 KB -> 6 blocks/CU (LDS); VGPR ~110 -> ~16 waves/CU.
// ---------------------------------------------------------------------------
__global__ __launch_bounds__(256, 4) void apply_W(const float* __restrict__ x,
                                                  const int*   __restrict__ r_idx,
                                                  const unsigned short* __restrict__ WgT,
                                                  float* __restrict__ out) {
    __shared__ alignas(16) unsigned char ldsA[128 * 128];   // 16384 B: A tile
    __shared__ alignas(16) unsigned char ldsB[64 * 128];    //  8192 B: B tile
    const int blk  = blockIdx.x;
    const int b    = blk >> 1;
    const int half = blk & 1;
    const size_t rowbase = (size_t)b * NN + half * 128;
    const int t = threadIdx.x;

    const int e = r_idx[b];   // uniform

    // ---- stage B: WgT[e] = 64 rows(c) x 64 bf16(d) = 2048 dwords, swizzled
    {
        const unsigned* src = (const unsigned*)(WgT + (size_t)e * (DD * DD));
        #pragma unroll
        for (int p = 0; p < 8; ++p) {
            int i = p * 256 + t;                 // dword index
            int c = i >> 5;                      // B row (W column)
            int off = (i & 31) * 4;              // byte offset within row
            *(unsigned*)&ldsB[c * 128 + (off ^ ((c & 7) << 4))] = src[i];
        }
    }

    // ---- stage A: x rows stripped of col0, fp32->bf16, swizzled.
    // Wave wv stages rows wv+4k, k=0..31 (ALL 128 rows — R5 bug fixed).
    {
        const float* xb = x + rowbase * DIMV;
        const int lane = t & 63;
        const int wv   = t >> 6;
        #pragma unroll
        for (int k = 0; k < 32; ++k) {
            int row = wv + 4 * k;
            float v = xb[row * DIMV + 1 + lane];
            int off = (lane * 2) ^ ((row & 7) << 4);
            *(unsigned short*)&ldsA[row * 128 + off] = f2bf(v);
        }
        // col-0 passthrough (lines already fetched by the stage reads)
        if (t < 128) out[(rowbase + t) * DIMV] = xb[t * DIMV];
    }
    __syncthreads();

    const int w     = t >> 6;     // wave 0..3: rows [32w, 32w+32)
    const int l     = t & 63;
    const int lrow  = l & 15;     // fragment M/N index
    const int kslot = l >> 4;     // fragment K group (8 bf16 each)
    const int r0    = w * 32;

    // A fragments: [row-tile][k-block]
    short8 afrg[2][2];
    #pragma unroll
    for (int rt = 0; rt < 2; ++rt)
        #pragma unroll
        for (int kb = 0; kb < 2; ++kb) {
            int row = r0 + rt * 16 + lrow;
            int off = ((kb << 6) | (kslot << 4)) ^ ((row & 7) << 4);
            afrg[rt][kb] = *(const short8*)&ldsA[row * 128 + off];
        }
    // B fragments: [col-tile][k-block]
    short8 bfrg[4][2];
    #pragma unroll
    for (int ct = 0; ct < 4; ++ct)
        #pragma unroll
        for (int kb = 0; kb < 2; ++kb) {
            int col = ct * 16 + lrow;
            int off = ((kb << 6) | (kslot << 4)) ^ ((col & 7) << 4);
            bfrg[ct][kb] = *(const short8*)&ldsB[col * 128 + off];
        }

    // 16 MFMAs, independent accumulators (good ILP)
    f32x4 acc[2][4];
    #pragma unroll
    for (int rt = 0; rt < 2; ++rt)
        #pragma unroll
        for (int ct = 0; ct < 4; ++ct) {
            f32x4 c0 = {0.f, 0.f, 0.f, 0.f};
            c0 = __builtin_amdgcn_mfma_f32_16x16x32_bf16(afrg[rt][0], bfrg[ct][0], c0, 0, 0, 0);
            c0 = __builtin_amdgcn_mfma_f32_16x16x32_bf16(afrg[rt][1], bfrg[ct][1], c0, 0, 0, 0);
            acc[rt][ct] = c0;
        }

    // store: C/D layout col=lane&15, row=(lane>>4)*4+reg
    #pragma unroll
    for (int rt = 0; rt < 2; ++rt) {
        const size_t rowb = rowbase + r0 + rt * 16 + kslot * 4;
        #pragma unroll
        for (int ct = 0; ct < 4; ++ct) {
            #pragma unroll
            for (int rg = 0; rg < 4; ++rg) {
                out[(rowb + rg) * DIMV + 1 + ct * 16 + lrow] = acc[rt][ct][rg];
            }
        }
    }
}

extern "C" void kernel_launch(void* const* d_in, const int* in_sizes, int n_in,
                              void* d_out, int out_size, void* d_ws, size_t ws_size,
                              hipStream_t stream) {
    const float* x         = (const float*)d_in[0];
    const int*   r_idx     = (const int*)d_in[1];
    const float* emb       = (const float*)d_in[2];
    const float* flip_sign = (const float*)d_in[3];
    float* out = (float*)d_out;
    unsigned short* WgT = (unsigned short*)d_ws;   // 512*64*64*2 = 4 MB bf16 W^T

    build_W<<<NUM_EMB, 256, 0, stream>>>(emb, flip_sign, r_idx, WgT, out);
    apply_W<<<BB * 2, 256, 0, stream>>>(x, r_idx, WgT, out);
}